// Round 8
// baseline (78.441 us; speedup 1.0000x reference)
//
#include <hip/hip_runtime.h>
#include <hip/hip_bf16.h>
#include <math.h>
#include <stdint.h>

#define DM 4096
#define NEXP 64
#define BK 64              // k per chunk
#define NCH 64             // K chunks total
#define KGRP 8             // kgroups; block covers 8 chunks = K 512
#define TILE_T 16          // tokens per tile
#define TILES_PB 8         // tiles per block -> 128 tokens
#define NTOK 16384

typedef short bf16x8 __attribute__((ext_vector_type(8)));
typedef float f32x4  __attribute__((ext_vector_type(4)));

// RN split: x = hi + lo + f, |f| <= 2^-18 |x|. lo = x - hi is Sterbenz-exact.
__device__ __forceinline__ void split2(float f0, float f1, uint32_t& hw, uint32_t& lw) {
    float2 ff; ff.x = f0; ff.y = f1;
    __hip_bfloat162 h = __float22bfloat162_rn(ff);
    union { __hip_bfloat162 b; uint32_t u; } ch; ch.b = h;
    hw = ch.u;
    float h0 = __bfloat162float(h.x);
    float h1 = __bfloat162float(h.y);
    float2 gg; gg.x = f0 - h0; gg.y = f1 - h1;
    __hip_bfloat162 l = __float22bfloat162_rn(gg);
    union { __hip_bfloat162 b; uint32_t u; } cl; cl.b = l;
    lw = cl.u;
}

// ---------------- pre-pass: W fp32 -> RN bf16 hi/lo, fragment-ordered blob ----------------
// blob byte layout: c*16384 + ks*4096 + n4*1024 + lane*16 (hi; +8192 for lo)
// where lane = (e&15) | ((kgran&3)<<4), n4 = e>>4, ks = kgran>>2.
__global__ __launch_bounds__(512) void wsplit_kernel(const float* __restrict__ W,
                                                     char* __restrict__ blob) {
    const int c   = blockIdx.x;        // 0..63
    const int tid = threadIdx.x;       // 0..511
    const int e   = tid >> 3;          // expert 0..63
    const int g   = tid & 7;           // k-granule 0..7 (8 bf16 each)

    const float* src = W + (size_t)e * DM + c * BK + g * 8;
    float x[8];
    *(float4*)(x)     = *(const float4*)(src);
    *(float4*)(x + 4) = *(const float4*)(src + 4);

    uint32_t hiw[4], low[4];
#pragma unroll
    for (int j = 0; j < 4; ++j) split2(x[2 * j], x[2 * j + 1], hiw[j], low[j]);

    const int ks = g >> 2;
    const int ln = (e & 15) | ((g & 3) << 4);
    const int n4 = e >> 4;
    const size_t base = (size_t)c * 16384 + (size_t)ks * 4096 + (size_t)n4 * 1024 + (size_t)ln * 16;
    *(uint4*)(blob + base)        = *(uint4*)hiw;   // hi plane
    *(uint4*)(blob + base + 8192) = *(uint4*)low;   // lo plane
}

// ---------------- kernel 1: partial logits, B register-resident ----------------
// 512 threads = 8 waves. Block b: kgroup g = b&7 (chunks g*8..g*8+7, wave wv
// owns chunk g*8+wv), tokens [ (b>>3)*128, +128 ) in 8 tiles of 16.
// B fragments (16 x bf16x8 = 64 VGPR) loaded ONCE; K-loop is pure
// A-stream + split + MFMA, no barriers except the per-tile LDS reduce.
__global__ __launch_bounds__(512, 4) void partial_kernel(
    const float* __restrict__ X,
    const char* __restrict__ blob,
    float* __restrict__ pws)
{
    __shared__ float part[KGRP][TILE_T][66];   // padded: kg-groups land on disjoint banks

    const int tid  = threadIdx.x;
    const int lane = tid & 63;
    const int wv   = tid >> 6;                 // 0..7
    const int b    = blockIdx.x;
    const int g    = b & 7;                    // kgroup
    const long tokbase = (long)(b >> 3) * (TILES_PB * TILE_T);
    const int c    = g * 8 + wv;               // this wave's chunk

    // ---- B fragments: load once, keep in registers ----
    const char* bb = blob + (size_t)c * 16384;
    bf16x8 bh[2][4], bl[2][4];
#pragma unroll
    for (int ks = 0; ks < 2; ++ks)
#pragma unroll
        for (int n = 0; n < 4; ++n) {
            const size_t off = (size_t)ks * 4096 + (size_t)n * 1024 + (size_t)lane * 16;
            bh[ks][n] = *(const bf16x8*)(bb + off);
            bl[ks][n] = *(const bf16x8*)(bb + 8192 + off);
        }

    const int tk = lane & 15;                  // A row / C col
    const int kg = lane >> 4;                  // k-granule
    const float* abase = X + (size_t)(tokbase + tk) * DM + c * BK + kg * 8;

    float xr[2][8];                            // [ks][8] A staging (rotated)
    auto loadA = [&](int t) {
        const float* p = abase + (size_t)t * TILE_T * DM;
#pragma unroll
        for (int ks = 0; ks < 2; ++ks) {
            *(float4*)(xr[ks])     = *(const float4*)(p + ks * 32);
            *(float4*)(xr[ks] + 4) = *(const float4*)(p + ks * 32 + 4);
        }
    };

    loadA(0);
#pragma unroll 1
    for (int t = 0; t < TILES_PB; ++t) {
        // split current A (frees xr), then issue next tile's loads
        bf16x8 ah[2], al[2];
#pragma unroll
        for (int ks = 0; ks < 2; ++ks) {
            uint32_t hw[4], lw[4];
#pragma unroll
            for (int j = 0; j < 4; ++j)
                split2(xr[ks][2 * j], xr[ks][2 * j + 1], hw[j], lw[j]);
            ah[ks] = *(bf16x8*)hw;
            al[ks] = *(bf16x8*)lw;
        }
        if (t + 1 < TILES_PB) loadA(t + 1);

        f32x4 acc[4];
#pragma unroll
        for (int n = 0; n < 4; ++n) acc[n] = (f32x4)0.0f;
#pragma unroll
        for (int ks = 0; ks < 2; ++ks)
#pragma unroll
            for (int n = 0; n < 4; ++n) {
                acc[n] = __builtin_amdgcn_mfma_f32_16x16x32_bf16(ah[ks], bh[ks][n], acc[n], 0, 0, 0);
                acc[n] = __builtin_amdgcn_mfma_f32_16x16x32_bf16(ah[ks], bl[ks][n], acc[n], 0, 0, 0);
                acc[n] = __builtin_amdgcn_mfma_f32_16x16x32_bf16(al[ks], bh[ks][n], acc[n], 0, 0, 0);
                acc[n] = __builtin_amdgcn_mfma_f32_16x16x32_bf16(al[ks], bl[ks][n], acc[n], 0, 0, 0);
            }

        // per-tile reduce over the 8 chunk-waves
#pragma unroll
        for (int n = 0; n < 4; ++n)
#pragma unroll
            for (int r = 0; r < 4; ++r)
                part[wv][kg * 4 + r][n * 16 + tk] = acc[n][r];
        __syncthreads();

#pragma unroll
        for (int i = 0; i < 2; ++i) {
            const int cell = tid + i * 512;
            const int t16 = cell >> 6;
            const int e   = cell & 63;
            float s = part[0][t16][e];
#pragma unroll
            for (int w = 1; w < KGRP; ++w) s += part[w][t16][e];
            pws[((size_t)(tokbase + t * TILE_T + t16) * KGRP + g) * NEXP + e] = s;
        }
        __syncthreads();
    }
}

// ---------------- kernel 2: sum kgroups + bias + softmax + top-2 + scatter ----------------
__global__ __launch_bounds__(256) void finalize_kernel(
    const float* __restrict__ pws,
    const float* __restrict__ Bv,
    float* __restrict__ out)
{
    const int tid  = threadIdx.x;
    const int lane = tid & 63;
    const int wid  = blockIdx.x * 4 + (tid >> 6);   // 0..4095
    const float bias = Bv[lane];

#pragma unroll 1
    for (int j = 0; j < 4; ++j) {
        const long tok = (long)wid * 4 + j;
        const float* p = pws + (size_t)tok * (KGRP * NEXP) + lane;
        float s = p[0];
#pragma unroll
        for (int g2 = 1; g2 < KGRP; ++g2) s += p[g2 * NEXP];
        float v = s + bias;

        float m1 = v;        int i1 = lane;
        float m2 = -3.4e38f; int i2 = 127;
#pragma unroll
        for (int s2 = 1; s2 < 64; s2 <<= 1) {
            float om1 = __shfl_xor(m1, s2, 64);
            int   oi1 = __shfl_xor(i1, s2, 64);
            float om2 = __shfl_xor(m2, s2, 64);
            int   oi2 = __shfl_xor(i2, s2, 64);
            bool bw2 = (om1 > m1) || (om1 == m1 && oi1 < i1);
            float l1v = bw2 ? m1 : om1;  int l1i = bw2 ? i1 : oi1;
            float w2v = bw2 ? om2 : m2;  int w2i = bw2 ? oi2 : i2;
            if (bw2) { m1 = om1; i1 = oi1; }
            bool tw = (l1v > w2v) || (l1v == w2v && l1i < w2i);
            m2 = tw ? l1v : w2v;  i2 = tw ? l1i : w2i;
        }

        float pexp = expf(v - m1);
        float ssum = pexp;
#pragma unroll
        for (int s2 = 1; s2 < 64; s2 <<= 1) ssum += __shfl_xor(ssum, s2, 64);

        float sc = (lane == i1 || lane == i2) ? (pexp / ssum) : 0.0f;
        out[tok * NEXP + lane] = sc;
    }
}

extern "C" void kernel_launch(void* const* d_in, const int* in_sizes, int n_in,
                              void* d_out, int out_size, void* d_ws, size_t ws_size,
                              hipStream_t stream) {
    const float* X  = (const float*)d_in[0];   // [4,4096,4096] fp32
    const float* W  = (const float*)d_in[1];   // [64,4096] fp32
    const float* Bv = (const float*)d_in[2];   // [64] fp32
    float* out = (float*)d_out;                // [4,4096,64] fp32

    char*  blob = (char*)d_ws;                             // 1 MiB
    float* pws  = (float*)((char*)d_ws + (1 << 20));       // 32 MiB partials

    wsplit_kernel<<<dim3(NCH), dim3(512), 0, stream>>>(W, blob);

    const int nblocks = (NTOK / (TILES_PB * TILE_T)) * KGRP;   // 1024
    partial_kernel<<<dim3(nblocks), dim3(512), 0, stream>>>(X, blob, pws);

    finalize_kernel<<<dim3(NTOK / (4 * 4)), dim3(256), 0, stream>>>(pws, Bv, out);
}

// Round 9
// 76.937 us; speedup vs baseline: 1.0195x; 1.0195x over previous
//
#include <hip/hip_runtime.h>
#include <hip/hip_bf16.h>
#include <math.h>
#include <stdint.h>

#define DM 4096
#define NEXP 64
#define BK 64              // k per chunk
#define NCH (DM / BK)      // 64 chunks
#define TOKW 32            // tokens per block
#define KSPLIT 8           // waves per block, each owns NCH/KSPLIT chunks
#define CHPS (NCH / KSPLIT)

typedef short bf16x8 __attribute__((ext_vector_type(8)));
typedef float f32x4  __attribute__((ext_vector_type(4)));

// RN split: x = hi + lo + f, |f| <= 2^-18 |x|. lo = x - hi is Sterbenz-exact.
__device__ __forceinline__ void split2(float f0, float f1, uint32_t& hw, uint32_t& lw) {
    float2 ff; ff.x = f0; ff.y = f1;
    __hip_bfloat162 h = __float22bfloat162_rn(ff);
    union { __hip_bfloat162 b; uint32_t u; } ch; ch.b = h;
    hw = ch.u;
    float h0 = __bfloat162float(h.x);
    float h1 = __bfloat162float(h.y);
    float2 gg; gg.x = f0 - h0; gg.y = f1 - h1;
    __hip_bfloat162 l = __float22bfloat162_rn(gg);
    union { __hip_bfloat162 b; uint32_t u; } cl; cl.b = l;
    lw = cl.u;
}

// ---------------- pre-pass: W fp32 -> RN bf16 hi/lo, fragment-ordered blob ----------------
// blob byte layout: c*16384 + ks*4096 + n4*1024 + lane*16 (hi; +8192 for lo)
// where lane = (e&15) | ((kgran&3)<<4), n4 = e>>4, ks = kgran>>2.
// 256 blocks (64 chunks x 4 expert-quarters) so the pre-pass spreads across CUs.
__global__ __launch_bounds__(128) void wsplit_kernel(const float* __restrict__ W,
                                                     char* __restrict__ blob) {
    const int c   = blockIdx.x;        // 0..63
    const int eq  = blockIdx.y;        // 0..3
    const int tid = threadIdx.x;       // 0..127
    const int e   = eq * 16 + (tid >> 3);  // expert 0..63
    const int g   = tid & 7;           // k-granule 0..7 (8 bf16 each)

    const float* src = W + (size_t)e * DM + c * BK + g * 8;
    float x[8];
    *(float4*)(x)     = *(const float4*)(src);
    *(float4*)(x + 4) = *(const float4*)(src + 4);

    uint32_t hiw[4], low[4];
#pragma unroll
    for (int j = 0; j < 4; ++j) split2(x[2 * j], x[2 * j + 1], hiw[j], low[j]);

    const int ks = g >> 2;
    const int ln = (e & 15) | ((g & 3) << 4);
    const int n4 = e >> 4;
    const size_t base = (size_t)c * 16384 + (size_t)ks * 4096 + (size_t)n4 * 1024 + (size_t)ln * 16;
    *(uint4*)(blob + base)        = *(uint4*)hiw;   // hi plane
    *(uint4*)(blob + base + 8192) = *(uint4*)low;   // lo plane
}

// ---------------- main kernel ----------------
// 512 threads = 8 waves, no barriers in the K-loop. Wave w owns K-chunks
// [w*CHPS,(w+1)*CHPS) for the block's 32 tokens. A (=X) fragments load
// per-lane direct from global; B fragments stream from the L2-resident blob.
// 3-product split GEMM: hh + hl + lh (ll term ~3e-6 logit error, dropped).
__global__ __launch_bounds__(512, 4) void router_mfma_kernel(
    const float* __restrict__ X,
    const char* __restrict__ blob,
    const float* __restrict__ Bv,
    float* __restrict__ out)
{
    __shared__ float part[KSPLIT][TOKW][NEXP];   // 64 KiB

    const int tid  = threadIdx.x;      // 0..511
    const int lane = tid & 63;
    const int wv   = tid >> 6;         // 0..7 = K-slice
    const long tok0 = (long)blockIdx.x * TOKW;

    const int tk = lane & 15;          // token-within-16 / expert col
    const int kg = lane >> 4;          // k-granule within 32-k subtile

    // per-lane A row bases (floats), at this wave's K-slice origin
    const float* a0 = X + (size_t)(tok0 + tk) * DM + (size_t)wv * (CHPS * BK) + kg * 8;
    const float* a1 = a0 + (size_t)16 * DM;
    const char*  bw = blob + (size_t)(wv * CHPS) * 16384;

    f32x4 acc[2][4];
#pragma unroll
    for (int m = 0; m < 2; ++m)
#pragma unroll
        for (int n = 0; n < 4; ++n) acc[m][n] = (f32x4)0.0f;

#pragma unroll 1
    for (int ci = 0; ci < CHPS; ++ci) {
        const char* bb = bw + (size_t)ci * 16384;

        // ---- A: 8 floats per (m, ks), per-lane direct from global ----
        float ar[2][2][8];   // [m][ks][8]
#pragma unroll
        for (int m = 0; m < 2; ++m) {
            const float* am = (m == 0) ? a0 : a1;
#pragma unroll
            for (int ks = 0; ks < 2; ++ks) {
                const float* p = am + ci * BK + ks * 32;
                *(float4*)(ar[m][ks])     = *(const float4*)(p);
                *(float4*)(ar[m][ks] + 4) = *(const float4*)(p + 4);
            }
        }

        // split to fragments
        bf16x8 ah[2][2], al[2][2];   // [ks][m]
#pragma unroll
        for (int m = 0; m < 2; ++m)
#pragma unroll
            for (int ks = 0; ks < 2; ++ks) {
                uint32_t hw[4], lw[4];
#pragma unroll
                for (int j = 0; j < 4; ++j)
                    split2(ar[m][ks][2 * j], ar[m][ks][2 * j + 1], hw[j], lw[j]);
                ah[ks][m] = *(bf16x8*)hw;
                al[ks][m] = *(bf16x8*)lw;
            }

        // ---- B from L2 (fragment-ordered blob) + MFMA (3 products) ----
#pragma unroll
        for (int ks = 0; ks < 2; ++ks) {
#pragma unroll
            for (int n = 0; n < 4; ++n) {
                const size_t bo = (size_t)ks * 4096 + (size_t)n * 1024 + (size_t)lane * 16;
                bf16x8 bh = *(const bf16x8*)(bb + bo);
                bf16x8 bl = *(const bf16x8*)(bb + 8192 + bo);
#pragma unroll
                for (int m = 0; m < 2; ++m) {
                    acc[m][n] = __builtin_amdgcn_mfma_f32_16x16x32_bf16(ah[ks][m], bh, acc[m][n], 0, 0, 0);
                    acc[m][n] = __builtin_amdgcn_mfma_f32_16x16x32_bf16(ah[ks][m], bl, acc[m][n], 0, 0, 0);
                    acc[m][n] = __builtin_amdgcn_mfma_f32_16x16x32_bf16(al[ks][m], bh, acc[m][n], 0, 0, 0);
                }
            }
        }
    }

    // ---- write per-slice partial logits: token = m*16 + kg*4 + r, expert = n*16 + tk ----
#pragma unroll
    for (int m = 0; m < 2; ++m)
#pragma unroll
        for (int n = 0; n < 4; ++n)
#pragma unroll
            for (int r = 0; r < 4; ++r)
                part[wv][m * 16 + kg * 4 + r][n * 16 + tk] = acc[m][n][r];
    __syncthreads();

    // ---- reduce over K-slices: 2048 cells, 4 per thread ----
#pragma unroll
    for (int i = 0; i < 4; ++i) {
        const int cell = tid + i * 512;
        const int t = cell >> 6;
        const int e = cell & 63;
        float s = part[0][t][e];
#pragma unroll
        for (int w = 1; w < KSPLIT; ++w) s += part[w][t][e];
        part[0][t][e] = s;
    }
    __syncthreads();

    // ---- epilogue: bias + softmax + top-2 + dense scatter (lane = expert) ----
    const float bias = Bv[lane];
#pragma unroll 1
    for (int j = 0; j < TOKW / KSPLIT; ++j) {
        const int t = wv * (TOKW / KSPLIT) + j;
        float v = part[0][t][lane] + bias;

        float m1 = v;        int i1 = lane;
        float m2 = -3.4e38f; int i2 = 127;
#pragma unroll
        for (int s = 1; s < 64; s <<= 1) {
            float om1 = __shfl_xor(m1, s, 64);
            int   oi1 = __shfl_xor(i1, s, 64);
            float om2 = __shfl_xor(m2, s, 64);
            int   oi2 = __shfl_xor(i2, s, 64);
            bool bw2 = (om1 > m1) || (om1 == m1 && oi1 < i1);
            float l1v = bw2 ? m1 : om1;  int l1i = bw2 ? i1 : oi1;
            float w2v = bw2 ? om2 : m2;  int w2i = bw2 ? oi2 : i2;
            if (bw2) { m1 = om1; i1 = oi1; }
            bool tw = (l1v > w2v) || (l1v == w2v && l1i < w2i);
            m2 = tw ? l1v : w2v;  i2 = tw ? l1i : w2i;
        }

        float p = expf(v - m1);
        float ssum = p;
#pragma unroll
        for (int s = 1; s < 64; s <<= 1) ssum += __shfl_xor(ssum, s, 64);

        float sc = (lane == i1 || lane == i2) ? (p / ssum) : 0.0f;
        out[(size_t)(tok0 + t) * NEXP + lane] = sc;
    }
}

extern "C" void kernel_launch(void* const* d_in, const int* in_sizes, int n_in,
                              void* d_out, int out_size, void* d_ws, size_t ws_size,
                              hipStream_t stream) {
    const float* X  = (const float*)d_in[0];   // [4,4096,4096] fp32
    const float* W  = (const float*)d_in[1];   // [64,4096] fp32
    const float* Bv = (const float*)d_in[2];   // [64] fp32
    float* out = (float*)d_out;                // [4,4096,64] fp32

    // W split blob: 64 chunks * 16 KiB = 1 MiB in d_ws
    char* blob = (char*)d_ws;
    wsplit_kernel<<<dim3(NCH, 4), dim3(128), 0, stream>>>(W, blob);

    const int n_tokens = 4 * 4096;             // 16384
    router_mfma_kernel<<<dim3(n_tokens / TOKW), dim3(512), 0, stream>>>(X, blob, Bv, out);
}

// Round 10
// 74.925 us; speedup vs baseline: 1.0469x; 1.0269x over previous
//
#include <hip/hip_runtime.h>
#include <hip/hip_bf16.h>
#include <math.h>
#include <stdint.h>

#define DM 4096
#define NEXP 64
#define BK 64              // k per chunk
#define NCH (DM / BK)      // 64 chunks
#define TOKW 32            // tokens per block
#define KSPLIT 8           // waves per block, each owns NCH/KSPLIT chunks
#define CHPS (NCH / KSPLIT)

typedef short bf16x8 __attribute__((ext_vector_type(8)));
typedef float f32x4  __attribute__((ext_vector_type(4)));

// RN split: x = hi + lo + f, |f| <= 2^-18 |x|. lo = x - hi is Sterbenz-exact.
__device__ __forceinline__ void split2(float f0, float f1, uint32_t& hw, uint32_t& lw) {
    float2 ff; ff.x = f0; ff.y = f1;
    __hip_bfloat162 h = __float22bfloat162_rn(ff);
    union { __hip_bfloat162 b; uint32_t u; } ch; ch.b = h;
    hw = ch.u;
    float h0 = __bfloat162float(h.x);
    float h1 = __bfloat162float(h.y);
    float2 gg; gg.x = f0 - h0; gg.y = f1 - h1;
    __hip_bfloat162 l = __float22bfloat162_rn(gg);
    union { __hip_bfloat162 b; uint32_t u; } cl; cl.b = l;
    lw = cl.u;
}

// ---------------- pre-pass: W fp32 -> RN bf16 hi/lo, fragment-ordered blob ----------------
// blob byte layout: c*16384 + ks*4096 + n4*1024 + lane*16 (hi; +8192 for lo)
// where lane = (e&15) | ((kgran&3)<<4), n4 = e>>4, ks = kgran>>2.
// 256 blocks (64 chunks x 4 expert-quarters) so the pre-pass spreads across CUs.
__global__ __launch_bounds__(128) void wsplit_kernel(const float* __restrict__ W,
                                                     char* __restrict__ blob) {
    const int c   = blockIdx.x;        // 0..63
    const int eq  = blockIdx.y;        // 0..3
    const int tid = threadIdx.x;       // 0..127
    const int e   = eq * 16 + (tid >> 3);  // expert 0..63
    const int g   = tid & 7;           // k-granule 0..7 (8 bf16 each)

    const float* src = W + (size_t)e * DM + c * BK + g * 8;
    float x[8];
    *(float4*)(x)     = *(const float4*)(src);
    *(float4*)(x + 4) = *(const float4*)(src + 4);

    uint32_t hiw[4], low[4];
#pragma unroll
    for (int j = 0; j < 4; ++j) split2(x[2 * j], x[2 * j + 1], hiw[j], low[j]);

    const int ks = g >> 2;
    const int ln = (e & 15) | ((g & 3) << 4);
    const int n4 = e >> 4;
    const size_t base = (size_t)c * 16384 + (size_t)ks * 4096 + (size_t)n4 * 1024 + (size_t)ln * 16;
    *(uint4*)(blob + base)        = *(uint4*)hiw;   // hi plane
    *(uint4*)(blob + base + 8192) = *(uint4*)low;   // lo plane
}

// ---------------- main kernel ----------------
// 512 threads = 8 waves, no barriers in the K-loop. Wave w owns K-chunks
// [w*CHPS,(w+1)*CHPS) for the block's 32 tokens. A (=X) fragments load
// per-lane direct from global; B fragments stream from the L2-resident blob.
// 3-product split GEMM: hh + hl + lh (ll term ~3e-6 logit error, dropped).
__global__ __launch_bounds__(512, 4) void router_mfma_kernel(
    const float* __restrict__ X,
    const char* __restrict__ blob,
    const float* __restrict__ Bv,
    float* __restrict__ out)
{
    __shared__ float part[KSPLIT][TOKW][NEXP];   // 64 KiB

    const int tid  = threadIdx.x;      // 0..511
    const int lane = tid & 63;
    const int wv   = tid >> 6;         // 0..7 = K-slice
    const long tok0 = (long)blockIdx.x * TOKW;

    const int tk = lane & 15;          // token-within-16 / expert col
    const int kg = lane >> 4;          // k-granule within 32-k subtile

    // per-lane A row bases (floats), at this wave's K-slice origin
    const float* a0 = X + (size_t)(tok0 + tk) * DM + (size_t)wv * (CHPS * BK) + kg * 8;
    const float* a1 = a0 + (size_t)16 * DM;
    const char*  bw = blob + (size_t)(wv * CHPS) * 16384;

    f32x4 acc[2][4];
#pragma unroll
    for (int m = 0; m < 2; ++m)
#pragma unroll
        for (int n = 0; n < 4; ++n) acc[m][n] = (f32x4)0.0f;

#pragma unroll 1
    for (int ci = 0; ci < CHPS; ++ci) {
        const char* bb = bw + (size_t)ci * 16384;

        // ---- A: 8 floats per (m, ks), per-lane direct from global ----
        float ar[2][2][8];   // [m][ks][8]
#pragma unroll
        for (int m = 0; m < 2; ++m) {
            const float* am = (m == 0) ? a0 : a1;
#pragma unroll
            for (int ks = 0; ks < 2; ++ks) {
                const float* p = am + ci * BK + ks * 32;
                *(float4*)(ar[m][ks])     = *(const float4*)(p);
                *(float4*)(ar[m][ks] + 4) = *(const float4*)(p + 4);
            }
        }

        // split to fragments
        bf16x8 ah[2][2], al[2][2];   // [ks][m]
#pragma unroll
        for (int m = 0; m < 2; ++m)
#pragma unroll
            for (int ks = 0; ks < 2; ++ks) {
                uint32_t hw[4], lw[4];
#pragma unroll
                for (int j = 0; j < 4; ++j)
                    split2(ar[m][ks][2 * j], ar[m][ks][2 * j + 1], hw[j], lw[j]);
                ah[ks][m] = *(bf16x8*)hw;
                al[ks][m] = *(bf16x8*)lw;
            }

        // ---- B from L2 (fragment-ordered blob) + MFMA (3 products) ----
#pragma unroll
        for (int ks = 0; ks < 2; ++ks) {
#pragma unroll
            for (int n = 0; n < 4; ++n) {
                const size_t bo = (size_t)ks * 4096 + (size_t)n * 1024 + (size_t)lane * 16;
                bf16x8 bh = *(const bf16x8*)(bb + bo);
                bf16x8 bl = *(const bf16x8*)(bb + 8192 + bo);
#pragma unroll
                for (int m = 0; m < 2; ++m) {
                    acc[m][n] = __builtin_amdgcn_mfma_f32_16x16x32_bf16(ah[ks][m], bh, acc[m][n], 0, 0, 0);
                    acc[m][n] = __builtin_amdgcn_mfma_f32_16x16x32_bf16(ah[ks][m], bl, acc[m][n], 0, 0, 0);
                    acc[m][n] = __builtin_amdgcn_mfma_f32_16x16x32_bf16(al[ks][m], bh, acc[m][n], 0, 0, 0);
                }
            }
        }
    }

    // ---- write per-slice partial logits: token = m*16 + kg*4 + r, expert = n*16 + tk ----
#pragma unroll
    for (int m = 0; m < 2; ++m)
#pragma unroll
        for (int n = 0; n < 4; ++n)
#pragma unroll
            for (int r = 0; r < 4; ++r)
                part[wv][m * 16 + kg * 4 + r][n * 16 + tk] = acc[m][n][r];
    __syncthreads();

    // ---- reduce over K-slices: 2048 cells, 4 per thread ----
#pragma unroll
    for (int i = 0; i < 4; ++i) {
        const int cell = tid + i * 512;
        const int t = cell >> 6;
        const int e = cell & 63;
        float s = part[0][t][e];
#pragma unroll
        for (int w = 1; w < KSPLIT; ++w) s += part[w][t][e];
        part[0][t][e] = s;
    }
    __syncthreads();

    // ---- epilogue: bias + softmax + top-2 + dense scatter (lane = expert) ----
    const float bias = Bv[lane];
#pragma unroll 1
    for (int j = 0; j < TOKW / KSPLIT; ++j) {
        const int t = wv * (TOKW / KSPLIT) + j;
        float v = part[0][t][lane] + bias;

        float m1 = v;        int i1 = lane;
        float m2 = -3.4e38f; int i2 = 127;
#pragma unroll
        for (int s = 1; s < 64; s <<= 1) {
            float om1 = __shfl_xor(m1, s, 64);
            int   oi1 = __shfl_xor(i1, s, 64);
            float om2 = __shfl_xor(m2, s, 64);
            int   oi2 = __shfl_xor(i2, s, 64);
            bool bw2 = (om1 > m1) || (om1 == m1 && oi1 < i1);
            float l1v = bw2 ? m1 : om1;  int l1i = bw2 ? i1 : oi1;
            float w2v = bw2 ? om2 : m2;  int w2i = bw2 ? oi2 : i2;
            if (bw2) { m1 = om1; i1 = oi1; }
            bool tw = (l1v > w2v) || (l1v == w2v && l1i < w2i);
            m2 = tw ? l1v : w2v;  i2 = tw ? l1i : w2i;
        }

        float p = expf(v - m1);
        float ssum = p;
#pragma unroll
        for (int s = 1; s < 64; s <<= 1) ssum += __shfl_xor(ssum, s, 64);

        float sc = (lane == i1 || lane == i2) ? (p / ssum) : 0.0f;
        out[(size_t)(tok0 + t) * NEXP + lane] = sc;
    }
}

extern "C" void kernel_launch(void* const* d_in, const int* in_sizes, int n_in,
                              void* d_out, int out_size, void* d_ws, size_t ws_size,
                              hipStream_t stream) {
    const float* X  = (const float*)d_in[0];   // [4,4096,4096] fp32
    const float* W  = (const float*)d_in[1];   // [64,4096] fp32
    const float* Bv = (const float*)d_in[2];   // [64] fp32
    float* out = (float*)d_out;                // [4,4096,64] fp32

    // W split blob: 64 chunks * 16 KiB = 1 MiB in d_ws
    char* blob = (char*)d_ws;
    wsplit_kernel<<<dim3(NCH, 4), dim3(128), 0, stream>>>(W, blob);

    const int n_tokens = 4 * 4096;             // 16384
    router_mfma_kernel<<<dim3(n_tokens / TOKW), dim3(512), 0, stream>>>(X, blob, Bv, out);
}

// Round 11
// 74.342 us; speedup vs baseline: 1.0551x; 1.0078x over previous
//
#include <hip/hip_runtime.h>
#include <hip/hip_bf16.h>
#include <math.h>
#include <stdint.h>

#define DM 4096
#define NEXP 64
#define BK 64              // k per chunk
#define NCH (DM / BK)      // 64 chunks
#define TOKW 32            // tokens per block
#define KSPLIT 8           // waves per block, each owns NCH/KSPLIT chunks
#define CHPS (NCH / KSPLIT)

typedef short bf16x8 __attribute__((ext_vector_type(8)));
typedef float f32x4  __attribute__((ext_vector_type(4)));

// RN split: x = hi + lo + f, |f| <= 2^-18 |x|. lo = x - hi is Sterbenz-exact.
__device__ __forceinline__ void split2(float f0, float f1, uint32_t& hw, uint32_t& lw) {
    float2 ff; ff.x = f0; ff.y = f1;
    __hip_bfloat162 h = __float22bfloat162_rn(ff);
    union { __hip_bfloat162 b; uint32_t u; } ch; ch.b = h;
    hw = ch.u;
    float h0 = __bfloat162float(h.x);
    float h1 = __bfloat162float(h.y);
    float2 gg; gg.x = f0 - h0; gg.y = f1 - h1;
    __hip_bfloat162 l = __float22bfloat162_rn(gg);
    union { __hip_bfloat162 b; uint32_t u; } cl; cl.b = l;
    lw = cl.u;
}

// ---------------- pre-pass: W fp32 -> RN bf16 hi/lo, fragment-ordered blob ----------------
// blob byte layout: c*16384 + ks*4096 + n4*1024 + lane*16 (hi; +8192 for lo)
// where lane = (e&15) | ((kgran&3)<<4), n4 = e>>4, ks = kgran>>2.
// 256 blocks (64 chunks x 4 expert-quarters) so the pre-pass spreads across CUs.
__global__ __launch_bounds__(128) void wsplit_kernel(const float* __restrict__ W,
                                                     char* __restrict__ blob) {
    const int c   = blockIdx.x;        // 0..63
    const int eq  = blockIdx.y;        // 0..3
    const int tid = threadIdx.x;       // 0..127
    const int e   = eq * 16 + (tid >> 3);  // expert 0..63
    const int g   = tid & 7;           // k-granule 0..7 (8 bf16 each)

    const float* src = W + (size_t)e * DM + c * BK + g * 8;
    float x[8];
    *(float4*)(x)     = *(const float4*)(src);
    *(float4*)(x + 4) = *(const float4*)(src + 4);

    uint32_t hiw[4], low[4];
#pragma unroll
    for (int j = 0; j < 4; ++j) split2(x[2 * j], x[2 * j + 1], hiw[j], low[j]);

    const int ks = g >> 2;
    const int ln = (e & 15) | ((g & 3) << 4);
    const int n4 = e >> 4;
    const size_t base = (size_t)c * 16384 + (size_t)ks * 4096 + (size_t)n4 * 1024 + (size_t)ln * 16;
    *(uint4*)(blob + base)        = *(uint4*)hiw;   // hi plane
    *(uint4*)(blob + base + 8192) = *(uint4*)low;   // lo plane
}

// ---------------- main kernel ----------------
// 512 threads = 8 waves, no barriers in the K-loop. Wave w owns K-chunks
// [w*CHPS,(w+1)*CHPS) for the block's 32 tokens. A (=X) fragments load
// per-lane direct from global; B fragments stream from the L2-resident blob.
// 3-product split GEMM: hh + hl + lh (ll term ~3e-6 logit error, dropped).
__global__ __launch_bounds__(512, 4) void router_mfma_kernel(
    const float* __restrict__ X,
    const char* __restrict__ blob,
    const float* __restrict__ Bv,
    float* __restrict__ out)
{
    __shared__ float part[KSPLIT][TOKW][NEXP];   // 64 KiB

    const int tid  = threadIdx.x;      // 0..511
    const int lane = tid & 63;
    const int wv   = tid >> 6;         // 0..7 = K-slice
    const long tok0 = (long)blockIdx.x * TOKW;

    const int tk = lane & 15;          // token-within-16 / expert col
    const int kg = lane >> 4;          // k-granule within 32-k subtile

    // per-lane A row bases (floats), at this wave's K-slice origin
    const float* a0 = X + (size_t)(tok0 + tk) * DM + (size_t)wv * (CHPS * BK) + kg * 8;
    const float* a1 = a0 + (size_t)16 * DM;
    const char*  bw = blob + (size_t)(wv * CHPS) * 16384;

    f32x4 acc[2][4];
#pragma unroll
    for (int m = 0; m < 2; ++m)
#pragma unroll
        for (int n = 0; n < 4; ++n) acc[m][n] = (f32x4)0.0f;

#pragma unroll 1
    for (int ci = 0; ci < CHPS; ++ci) {
        const char* bb = bw + (size_t)ci * 16384;

        // ---- A: 8 floats per (m, ks), per-lane direct from global ----
        float ar[2][2][8];   // [m][ks][8]
#pragma unroll
        for (int m = 0; m < 2; ++m) {
            const float* am = (m == 0) ? a0 : a1;
#pragma unroll
            for (int ks = 0; ks < 2; ++ks) {
                const float* p = am + ci * BK + ks * 32;
                *(float4*)(ar[m][ks])     = *(const float4*)(p);
                *(float4*)(ar[m][ks] + 4) = *(const float4*)(p + 4);
            }
        }

        // split to fragments
        bf16x8 ah[2][2], al[2][2];   // [ks][m]
#pragma unroll
        for (int m = 0; m < 2; ++m)
#pragma unroll
            for (int ks = 0; ks < 2; ++ks) {
                uint32_t hw[4], lw[4];
#pragma unroll
                for (int j = 0; j < 4; ++j)
                    split2(ar[m][ks][2 * j], ar[m][ks][2 * j + 1], hw[j], lw[j]);
                ah[ks][m] = *(bf16x8*)hw;
                al[ks][m] = *(bf16x8*)lw;
            }

        // ---- B from L2 (fragment-ordered blob) + MFMA (3 products) ----
#pragma unroll
        for (int ks = 0; ks < 2; ++ks) {
#pragma unroll
            for (int n = 0; n < 4; ++n) {
                const size_t bo = (size_t)ks * 4096 + (size_t)n * 1024 + (size_t)lane * 16;
                bf16x8 bh = *(const bf16x8*)(bb + bo);
                bf16x8 bl = *(const bf16x8*)(bb + 8192 + bo);
#pragma unroll
                for (int m = 0; m < 2; ++m) {
                    acc[m][n] = __builtin_amdgcn_mfma_f32_16x16x32_bf16(ah[ks][m], bh, acc[m][n], 0, 0, 0);
                    acc[m][n] = __builtin_amdgcn_mfma_f32_16x16x32_bf16(ah[ks][m], bl, acc[m][n], 0, 0, 0);
                    acc[m][n] = __builtin_amdgcn_mfma_f32_16x16x32_bf16(al[ks][m], bh, acc[m][n], 0, 0, 0);
                }
            }
        }
    }

    // ---- write per-slice partial logits: token = m*16 + kg*4 + r, expert = n*16 + tk ----
#pragma unroll
    for (int m = 0; m < 2; ++m)
#pragma unroll
        for (int n = 0; n < 4; ++n)
#pragma unroll
            for (int r = 0; r < 4; ++r)
                part[wv][m * 16 + kg * 4 + r][n * 16 + tk] = acc[m][n][r];
    __syncthreads();

    // ---- reduce over K-slices: 2048 cells, 4 per thread ----
#pragma unroll
    for (int i = 0; i < 4; ++i) {
        const int cell = tid + i * 512;
        const int t = cell >> 6;
        const int e = cell & 63;
        float s = part[0][t][e];
#pragma unroll
        for (int w = 1; w < KSPLIT; ++w) s += part[w][t][e];
        part[0][t][e] = s;
    }
    __syncthreads();

    // ---- epilogue: bias + softmax + top-2 + dense scatter (lane = expert) ----
    const float bias = Bv[lane];
#pragma unroll 1
    for (int j = 0; j < TOKW / KSPLIT; ++j) {
        const int t = wv * (TOKW / KSPLIT) + j;
        float v = part[0][t][lane] + bias;

        float m1 = v;        int i1 = lane;
        float m2 = -3.4e38f; int i2 = 127;
#pragma unroll
        for (int s = 1; s < 64; s <<= 1) {
            float om1 = __shfl_xor(m1, s, 64);
            int   oi1 = __shfl_xor(i1, s, 64);
            float om2 = __shfl_xor(m2, s, 64);
            int   oi2 = __shfl_xor(i2, s, 64);
            bool bw2 = (om1 > m1) || (om1 == m1 && oi1 < i1);
            float l1v = bw2 ? m1 : om1;  int l1i = bw2 ? i1 : oi1;
            float w2v = bw2 ? om2 : m2;  int w2i = bw2 ? oi2 : i2;
            if (bw2) { m1 = om1; i1 = oi1; }
            bool tw = (l1v > w2v) || (l1v == w2v && l1i < w2i);
            m2 = tw ? l1v : w2v;  i2 = tw ? l1i : w2i;
        }

        float p = expf(v - m1);
        float ssum = p;
#pragma unroll
        for (int s = 1; s < 64; s <<= 1) ssum += __shfl_xor(ssum, s, 64);

        float sc = (lane == i1 || lane == i2) ? (p / ssum) : 0.0f;
        out[(size_t)(tok0 + t) * NEXP + lane] = sc;
    }
}

extern "C" void kernel_launch(void* const* d_in, const int* in_sizes, int n_in,
                              void* d_out, int out_size, void* d_ws, size_t ws_size,
                              hipStream_t stream) {
    const float* X  = (const float*)d_in[0];   // [4,4096,4096] fp32
    const float* W  = (const float*)d_in[1];   // [64,4096] fp32
    const float* Bv = (const float*)d_in[2];   // [64] fp32
    float* out = (float*)d_out;                // [4,4096,64] fp32

    // W split blob: 64 chunks * 16 KiB = 1 MiB in d_ws
    char* blob = (char*)d_ws;
    wsplit_kernel<<<dim3(NCH, 4), dim3(128), 0, stream>>>(W, blob);

    const int n_tokens = 4 * 4096;             // 16384
    router_mfma_kernel<<<dim3(n_tokens / TOKW), dim3(512), 0, stream>>>(X, blob, Bv, out);
}